// Round 3
// baseline (84.556 us; speedup 1.0000x reference)
//
#include <hip/hip_runtime.h>
#include <hip/hip_bf16.h>

#define D_MODEL 1024
#define D_STATE 16
#define BATCH   4
#define SEQ     2048
#define ROWS    (BATCH*SEQ)   // 8192
#define WIN     64            // FIR window; decay<=0.55 => decay^64 < 1e-16

// ---------------------------------------------------------------------------
// K1: bx[row][n] = sum_d x[row][d] * B_w[n][d]     (row = b*SEQ + t)
// 256 threads = 16 dblk x 16 n, 8 rows/block. NO LDS staging: the 16 lanes
// sharing a dblk read IDENTICAL global addresses -> coalescer dedups to
// 4x16B requests per wave-load. x comes from HBM exactly once.
// ---------------------------------------------------------------------------
#define K1_ROWS 8
__global__ __launch_bounds__(256) void k_bx(const float* __restrict__ x,
                                            const float* __restrict__ Bw,
                                            float* __restrict__ bx) {
    __shared__ float red[4][K1_ROWS][16];
    const int tid  = threadIdx.x;
    const int n    = tid & 15;
    const int dblk = tid >> 4;              // 0..15, covers d = dblk*64 .. +63
    const int row0 = blockIdx.x * K1_ROWS;
    const int lane = tid & 63, wid = tid >> 6;

    // B_w[n][dblk*64 .. +63] in 16 float4 (compile-time indexed everywhere)
    float4 bw[16];
    const float4* bwp = reinterpret_cast<const float4*>(Bw + n * 1024 + dblk * 64);
#pragma unroll
    for (int jj = 0; jj < 16; ++jj) bw[jj] = bwp[jj];

    float s[K1_ROWS];
#pragma unroll
    for (int r = 0; r < K1_ROWS; ++r) s[r] = 0.f;

#pragma unroll
    for (int r = 0; r < K1_ROWS; ++r) {
        const float4* xp = reinterpret_cast<const float4*>(
            x + (size_t)(row0 + r) * 1024 + dblk * 64);
#pragma unroll
        for (int jj = 0; jj < 16; ++jj) {
            float4 xv = xp[jj];
            float4 b  = bw[jj];
            s[r] = fmaf(xv.x, b.x, s[r]); s[r] = fmaf(xv.y, b.y, s[r]);
            s[r] = fmaf(xv.z, b.z, s[r]); s[r] = fmaf(xv.w, b.w, s[r]);
        }
    }

    // reduce over dblk: fold 4 dblk groups within wave, then 4 waves via LDS
#pragma unroll
    for (int r = 0; r < K1_ROWS; ++r) {
        float v = s[r];
        v += __shfl_xor(v, 16);
        v += __shfl_xor(v, 32);
        s[r] = v;
    }
    if (lane < 16) {
#pragma unroll
        for (int r = 0; r < K1_ROWS; ++r) red[wid][r][lane] = s[r];
    }
    __syncthreads();
    if (tid < K1_ROWS * 16) {
        const int r = tid >> 4, n2 = tid & 15;
        float v = red[0][r][n2] + red[1][r][n2] + red[2][r][n2] + red[3][r][n2];
        bx[(size_t)(row0 + r) * D_STATE + n2] = v;
    }
}

// ---------------------------------------------------------------------------
// K2: KbarT[delta][n] = (1/1024) * sum_d decay[d][n]^delta
// decay^delta = exp2(delta * l2[d]),  l2[d] = -exp(A_log[d][n]) * log2(e).
// Grid: 16 blocks (one per n) x 256 threads; lane=delta, wave=d-chunk.
// Delta-parallel: 2 barriers total (was 128).
// ---------------------------------------------------------------------------
__global__ __launch_bounds__(256) void k_kbar(const float* __restrict__ A_log,
                                              float* __restrict__ KbarT) {
    const int n = blockIdx.x;
    const int tid = threadIdx.x;
    const int delta = tid & 63;             // lane = delta
    const int c     = tid >> 6;             // wave = d-chunk (256 d each)
    __shared__ float l2[D_MODEL];
    __shared__ float red[4][WIN];

    for (int d = tid; d < D_MODEL; d += 256) {
        float a = A_log[d * D_STATE + n];
        l2[d] = -expf(a) * 1.4426950408889634f;   // log2(decay)
    }
    __syncthreads();

    const float fdelta = (float)delta;
    float acc = 0.f;
    const int d0 = c * 256;
    for (int d = d0; d < d0 + 256; ++d)           // broadcast LDS reads (free)
        acc += exp2f(fdelta * l2[d]);
    red[c][delta] = acc;
    __syncthreads();
    if (tid < WIN)
        KbarT[tid * D_STATE + n] =
            (red[0][tid] + red[1][tid] + red[2][tid] + red[3][tid]) * (1.0f / 1024.0f);
}

// ---------------------------------------------------------------------------
// K3 (fused FIR + output): per block of 8 rows:
//   hm[r][n] = sum_delta KbarT[delta][n] * bx[row-delta][n]   (threads 0..127)
//   y = hm @ C_w^T + D*x ; out = layernorm(y)*gamma + beta
// 3 barriers total: y[8][4] buffered in registers, single reduction round-trip.
// ---------------------------------------------------------------------------
#define K4_ROWS 8
__global__ __launch_bounds__(256) void k_out(const float* __restrict__ x,
                                             const float* __restrict__ bxg,
                                             const float* __restrict__ KbarT,
                                             const float* __restrict__ Cw,
                                             const float* __restrict__ Dp,
                                             const float* __restrict__ gamma,
                                             const float* __restrict__ beta,
                                             float* __restrict__ out) {
    const int tid = threadIdx.x;
    const int row0 = blockIdx.x * K4_ROWS;
    const int lane = tid & 63, wid = tid >> 6;
    __shared__ float kb[WIN * D_STATE];           // [delta][n]
    __shared__ float hm_s[K4_ROWS][D_STATE];
    __shared__ float red_s[K4_ROWS][4], red_q[K4_ROWS][4];

    // stage Kbar (4 KB)
    for (int i = tid; i < WIN * D_STATE; i += 256) kb[i] = KbarT[i];

    // preload C_w rows d = 4*tid..+3 -> 64 VGPRs (overlaps kb staging)
    float4 cw[4][4];
#pragma unroll
    for (int j = 0; j < 4; ++j) {
        const float4* p = reinterpret_cast<const float4*>(Cw + (size_t)(tid * 4 + j) * D_STATE);
#pragma unroll
        for (int q = 0; q < 4; ++q) cw[j][q] = p[q];
    }
    const float4 Dv = reinterpret_cast<const float4*>(Dp)[tid];
    const float4 gv = reinterpret_cast<const float4*>(gamma)[tid];
    const float4 bv = reinterpret_cast<const float4*>(beta)[tid];
    __syncthreads();

    // FIR: threads 0..127 each own (r, n)
    if (tid < K4_ROWS * D_STATE) {
        const int r = tid >> 4, n = tid & 15;
        const int row = row0 + r;
        const int t = row & (SEQ - 1);
        const float* bp = bxg + (size_t)row * D_STATE + n;
        float acc = 0.f;
        if (t >= WIN - 1) {
#pragma unroll
            for (int delta = 0; delta < WIN; ++delta)
                acc = fmaf(kb[delta * D_STATE + n], bp[-(ptrdiff_t)delta * D_STATE], acc);
        } else {
            const int kw = t + 1;
            for (int delta = 0; delta < kw; ++delta)
                acc = fmaf(kb[delta * D_STATE + n], bp[-(ptrdiff_t)delta * D_STATE], acc);
        }
        hm_s[r][n] = acc;
    }
    __syncthreads();

    // Phase B: all 8 rows' y in registers; per-row wave-partial sums to LDS
    float y[K4_ROWS][4];
#pragma unroll
    for (int r = 0; r < K4_ROWS; ++r) {
        const size_t row = row0 + r;
        const float4* hmp = reinterpret_cast<const float4*>(&hm_s[r][0]);
        float4 h0 = hmp[0], h1 = hmp[1], h2 = hmp[2], h3 = hmp[3]; // broadcast
        float4 xv = reinterpret_cast<const float4*>(x + row * 1024)[tid];

#pragma unroll
        for (int j = 0; j < 4; ++j) {
            float a = 0.f;
            a = fmaf(h0.x, cw[j][0].x, a); a = fmaf(h0.y, cw[j][0].y, a);
            a = fmaf(h0.z, cw[j][0].z, a); a = fmaf(h0.w, cw[j][0].w, a);
            a = fmaf(h1.x, cw[j][1].x, a); a = fmaf(h1.y, cw[j][1].y, a);
            a = fmaf(h1.z, cw[j][1].z, a); a = fmaf(h1.w, cw[j][1].w, a);
            a = fmaf(h2.x, cw[j][2].x, a); a = fmaf(h2.y, cw[j][2].y, a);
            a = fmaf(h2.z, cw[j][2].z, a); a = fmaf(h2.w, cw[j][2].w, a);
            a = fmaf(h3.x, cw[j][3].x, a); a = fmaf(h3.y, cw[j][3].y, a);
            a = fmaf(h3.z, cw[j][3].z, a); a = fmaf(h3.w, cw[j][3].w, a);
            y[r][j] = a;
        }
        y[r][0] = fmaf(Dv.x, xv.x, y[r][0]);
        y[r][1] = fmaf(Dv.y, xv.y, y[r][1]);
        y[r][2] = fmaf(Dv.z, xv.z, y[r][2]);
        y[r][3] = fmaf(Dv.w, xv.w, y[r][3]);

        float s  = y[r][0] + y[r][1] + y[r][2] + y[r][3];
        float sq = y[r][0]*y[r][0] + y[r][1]*y[r][1] + y[r][2]*y[r][2] + y[r][3]*y[r][3];
#pragma unroll
        for (int off = 32; off; off >>= 1) {
            s  += __shfl_xor(s,  off);
            sq += __shfl_xor(sq, off);
        }
        if (lane == 0) { red_s[r][wid] = s; red_q[r][wid] = sq; }
    }
    __syncthreads();

    // Phase C: finalize LN for all rows (broadcast LDS reads), store
#pragma unroll
    for (int r = 0; r < K4_ROWS; ++r) {
        const size_t row = row0 + r;
        float ssum = red_s[r][0] + red_s[r][1] + red_s[r][2] + red_s[r][3];
        float ssq  = red_q[r][0] + red_q[r][1] + red_q[r][2] + red_q[r][3];
        float mu   = ssum * (1.0f / 1024.0f);
        float var  = ssq * (1.0f / 1024.0f) - mu * mu;
        float inv  = rsqrtf(var + 1e-5f);
        float4 o;
        o.x = fmaf((y[r][0] - mu) * inv, gv.x, bv.x);
        o.y = fmaf((y[r][1] - mu) * inv, gv.y, bv.y);
        o.z = fmaf((y[r][2] - mu) * inv, gv.z, bv.z);
        o.w = fmaf((y[r][3] - mu) * inv, gv.w, bv.w);
        reinterpret_cast<float4*>(out + row * 1024)[tid] = o;
    }
}

extern "C" void kernel_launch(void* const* d_in, const int* in_sizes, int n_in,
                              void* d_out, int out_size, void* d_ws, size_t ws_size,
                              hipStream_t stream) {
    (void)in_sizes; (void)n_in; (void)out_size; (void)ws_size;
    const float* x     = (const float*)d_in[0];
    const float* A_log = (const float*)d_in[1];
    const float* B_w   = (const float*)d_in[2];
    const float* C_w   = (const float*)d_in[3];
    const float* Dp    = (const float*)d_in[4];
    const float* gamma = (const float*)d_in[5];
    const float* beta  = (const float*)d_in[6];
    float* out = (float*)d_out;

    float* bx = (float*)d_ws;                       // ROWS*16 floats (512 KB)
    float* kb = bx + (size_t)ROWS * D_STATE;        // WIN*16 floats (4 KB)

    k_bx  <<<ROWS / K1_ROWS, 256, 0, stream>>>(x, B_w, bx);
    k_kbar<<<D_STATE,        256, 0, stream>>>(A_log, kb);
    k_out <<<ROWS / K4_ROWS, 256, 0, stream>>>(x, bx, kb, C_w, Dp, gamma, beta, out);
}

// Round 4
// 75.728 us; speedup vs baseline: 1.1166x; 1.1166x over previous
//
#include <hip/hip_runtime.h>
#include <hip/hip_bf16.h>

#define D_MODEL 1024
#define D_STATE 16
#define BATCH   4
#define SEQ     2048
#define ROWS    (BATCH*SEQ)   // 8192
#define WIN     64            // FIR window; decay<=0.55 => decay^64 < 1e-16

// ---------------------------------------------------------------------------
// K1: bx[row][n] = sum_d x[row][d] * B_w[n][d]
// 256 threads = 32 dblk (32-d slices) x 8 np (n-pairs). x staged in LDS with a
// per-chunk rotate swizzle: within each 128B chunk, float4 slot s holds logical
// sub-chunk (s - dblk) & 7. Read instr j hits slot (j+dblk)&7 -> the 8 dblk
// lanes of a wave cover all 8 slots = all 32 banks, conflict-free; the 8 np
// lanes are same-address broadcast (free). 64 ds_read_b128/thread (was 128).
// ---------------------------------------------------------------------------
#define K1_ROWS 8
__global__ __launch_bounds__(256, 4) void k_bx(const float* __restrict__ x,
                                               const float* __restrict__ Bw,
                                               float* __restrict__ bx) {
    __shared__ float xs[K1_ROWS][1024];
    __shared__ float red[4][8][K1_ROWS][2];   // [wave][np][row][q]
    const int tid  = threadIdx.x;
    const int np   = tid & 7;                 // n = 2*np, 2*np+1
    const int dblk = tid >> 3;                // 0..31 -> d in [dblk*32, +32)
    const int row0 = blockIdx.x * K1_ROWS;
    const int lane = tid & 63, wid = tid >> 6;

    // B slices: bw0/bw1[j] = Bw[2np(+1)][dblk*32 + 4j .. +3]   (64 VGPRs)
    float4 bw0[8], bw1[8];
    {
        const float4* p0 = reinterpret_cast<const float4*>(Bw + (size_t)(2 * np    ) * 1024 + dblk * 32);
        const float4* p1 = reinterpret_cast<const float4*>(Bw + (size_t)(2 * np + 1) * 1024 + dblk * 32);
#pragma unroll
        for (int j = 0; j < 8; ++j) { bw0[j] = p0[j]; bw1[j] = p1[j]; }
    }

    // stage 8 rows, swizzled: thread writes its float4 (logical sub-chunk tid&7
    // of chunk tid>>3) at slot ((tid&7) + chunk) & 7
    const int chunk = tid >> 3;
    const int slotw = ((tid & 7) + chunk) & 7;
#pragma unroll
    for (int r = 0; r < K1_ROWS; ++r) {
        float4 v = reinterpret_cast<const float4*>(x + (size_t)(row0 + r) * 1024)[tid];
        *reinterpret_cast<float4*>(&xs[r][chunk * 32 + slotw * 4]) = v;
    }
    __syncthreads();

    float a0[K1_ROWS], a1[K1_ROWS];
#pragma unroll
    for (int r = 0; r < K1_ROWS; ++r) { a0[r] = 0.f; a1[r] = 0.f; }

#pragma unroll
    for (int r = 0; r < K1_ROWS; ++r) {
#pragma unroll
        for (int j = 0; j < 8; ++j) {
            const int slot = (j + dblk) & 7;            // holds logical j
            float4 xv = *reinterpret_cast<const float4*>(&xs[r][dblk * 32 + slot * 4]);
            a0[r] = fmaf(xv.x, bw0[j].x, a0[r]); a0[r] = fmaf(xv.y, bw0[j].y, a0[r]);
            a0[r] = fmaf(xv.z, bw0[j].z, a0[r]); a0[r] = fmaf(xv.w, bw0[j].w, a0[r]);
            a1[r] = fmaf(xv.x, bw1[j].x, a1[r]); a1[r] = fmaf(xv.y, bw1[j].y, a1[r]);
            a1[r] = fmaf(xv.z, bw1[j].z, a1[r]); a1[r] = fmaf(xv.w, bw1[j].w, a1[r]);
        }
    }

    // reduce over dblk: in-wave dblk bits are lane>>3 -> xor 8,16,32
#pragma unroll
    for (int r = 0; r < K1_ROWS; ++r) {
        float v0 = a0[r], v1 = a1[r];
        v0 += __shfl_xor(v0, 8);  v1 += __shfl_xor(v1, 8);
        v0 += __shfl_xor(v0, 16); v1 += __shfl_xor(v1, 16);
        v0 += __shfl_xor(v0, 32); v1 += __shfl_xor(v1, 32);
        a0[r] = v0; a1[r] = v1;
    }
    if (lane < 8) {                                     // np = lane
#pragma unroll
        for (int r = 0; r < K1_ROWS; ++r) {
            red[wid][lane][r][0] = a0[r];
            red[wid][lane][r][1] = a1[r];
        }
    }
    __syncthreads();
    if (tid < K1_ROWS * 16) {
        const int r = tid >> 4, n = tid & 15;
        float v = red[0][n >> 1][r][n & 1] + red[1][n >> 1][r][n & 1]
                + red[2][n >> 1][r][n & 1] + red[3][n >> 1][r][n & 1];
        bx[(size_t)(row0 + r) * D_STATE + n] = v;
    }
}

// ---------------------------------------------------------------------------
// K2: KbarT[delta][n] = (1/1024) * sum_d decay[d][n]^delta   (delta-parallel)
// ---------------------------------------------------------------------------
__global__ __launch_bounds__(256) void k_kbar(const float* __restrict__ A_log,
                                              float* __restrict__ KbarT) {
    const int n = blockIdx.x;
    const int tid = threadIdx.x;
    const int delta = tid & 63;
    const int c     = tid >> 6;
    __shared__ float l2[D_MODEL];
    __shared__ float red[4][WIN];

    for (int d = tid; d < D_MODEL; d += 256) {
        float a = A_log[d * D_STATE + n];
        l2[d] = -expf(a) * 1.4426950408889634f;   // log2(decay)
    }
    __syncthreads();

    const float fdelta = (float)delta;
    float acc = 0.f;
    const int d0 = c * 256;
    for (int d = d0; d < d0 + 256; ++d)
        acc += exp2f(fdelta * l2[d]);
    red[c][delta] = acc;
    __syncthreads();
    if (tid < WIN)
        KbarT[tid * D_STATE + n] =
            (red[0][tid] + red[1][tid] + red[2][tid] + red[3][tid]) * (1.0f / 1024.0f);
}

// ---------------------------------------------------------------------------
// K3 (fused FIR + matvec + LN): 1024 threads (16 waves), 1 d per thread,
// 8 rows/block, grid 1024. ~50 VGPR -> 8 waves/SIMD occupancy.
// ---------------------------------------------------------------------------
#define K4_ROWS 8
__global__ __launch_bounds__(1024, 8) void k_out(const float* __restrict__ x,
                                                 const float* __restrict__ bxg,
                                                 const float* __restrict__ KbarT,
                                                 const float* __restrict__ Cw,
                                                 const float* __restrict__ Dp,
                                                 const float* __restrict__ gamma,
                                                 const float* __restrict__ beta,
                                                 float* __restrict__ out) {
    const int tid = threadIdx.x;                  // = d (0..1023)
    const int row0 = blockIdx.x * K4_ROWS;
    const int lane = tid & 63, wid = tid >> 6;    // 16 waves
    __shared__ float kb[WIN * D_STATE];           // [delta][n], 4 KB
    __shared__ float hm_s[K4_ROWS][D_STATE];
    __shared__ float red_s[K4_ROWS][16], red_q[K4_ROWS][16];
    __shared__ float fin[K4_ROWS][2];

    kb[tid] = KbarT[tid];                         // 1024 == WIN*D_STATE

    // C_w[d][0..15] -> 16 VGPRs
    const float4* cwp = reinterpret_cast<const float4*>(Cw + (size_t)tid * D_STATE);
    const float4 cw0 = cwp[0], cw1 = cwp[1], cw2 = cwp[2], cw3 = cwp[3];
    const float Dv = Dp[tid], gv = gamma[tid], bv = beta[tid];
    __syncthreads();

    // FIR: threads 0..127 own (r, n)
    if (tid < K4_ROWS * D_STATE) {
        const int r = tid >> 4, n = tid & 15;
        const int row = row0 + r;
        const int t = row & (SEQ - 1);
        const float* bp = bxg + (size_t)row * D_STATE + n;
        float acc = 0.f;
        if (t >= WIN - 1) {
#pragma unroll
            for (int delta = 0; delta < WIN; ++delta)
                acc = fmaf(kb[delta * D_STATE + n], bp[-(ptrdiff_t)delta * D_STATE], acc);
        } else {
            for (int delta = 0; delta <= t; ++delta)
                acc = fmaf(kb[delta * D_STATE + n], bp[-(ptrdiff_t)delta * D_STATE], acc);
        }
        hm_s[r][n] = acc;
    }
    __syncthreads();

    float y[K4_ROWS];
#pragma unroll
    for (int r = 0; r < K4_ROWS; ++r) {
        const float4* hmp = reinterpret_cast<const float4*>(&hm_s[r][0]);
        float4 h0 = hmp[0], h1 = hmp[1], h2 = hmp[2], h3 = hmp[3];   // broadcast
        float xv = x[(size_t)(row0 + r) * D_MODEL + tid];
        float a = 0.f;
        a = fmaf(h0.x, cw0.x, a); a = fmaf(h0.y, cw0.y, a);
        a = fmaf(h0.z, cw0.z, a); a = fmaf(h0.w, cw0.w, a);
        a = fmaf(h1.x, cw1.x, a); a = fmaf(h1.y, cw1.y, a);
        a = fmaf(h1.z, cw1.z, a); a = fmaf(h1.w, cw1.w, a);
        a = fmaf(h2.x, cw2.x, a); a = fmaf(h2.y, cw2.y, a);
        a = fmaf(h2.z, cw2.z, a); a = fmaf(h2.w, cw2.w, a);
        a = fmaf(h3.x, cw3.x, a); a = fmaf(h3.y, cw3.y, a);
        a = fmaf(h3.z, cw3.z, a); a = fmaf(h3.w, cw3.w, a);
        a = fmaf(Dv, xv, a);
        y[r] = a;

        float s = a, sq = a * a;
        s += __shfl_xor(s, 1);  sq += __shfl_xor(sq, 1);
        s += __shfl_xor(s, 2);  sq += __shfl_xor(sq, 2);
        s += __shfl_xor(s, 4);  sq += __shfl_xor(sq, 4);
        s += __shfl_xor(s, 8);  sq += __shfl_xor(sq, 8);
        s += __shfl_xor(s, 16); sq += __shfl_xor(sq, 16);
        s += __shfl_xor(s, 32); sq += __shfl_xor(sq, 32);
        if (lane == 0) { red_s[r][wid] = s; red_q[r][wid] = sq; }
    }
    __syncthreads();

    // second-level reduce: threads 0..127, 16-lane groups fold 16 wave-partials
    if (tid < K4_ROWS * 16) {
        const int r = tid >> 4, w = tid & 15;
        float s = red_s[r][w], sq = red_q[r][w];
        s += __shfl_xor(s, 1); sq += __shfl_xor(sq, 1);
        s += __shfl_xor(s, 2); sq += __shfl_xor(sq, 2);
        s += __shfl_xor(s, 4); sq += __shfl_xor(sq, 4);
        s += __shfl_xor(s, 8); sq += __shfl_xor(sq, 8);
        if (w == 0) {
            float mu  = s * (1.0f / 1024.0f);
            float var = sq * (1.0f / 1024.0f) - mu * mu;
            fin[r][0] = mu;
            fin[r][1] = rsqrtf(var + 1e-5f);
        }
    }
    __syncthreads();

#pragma unroll
    for (int r = 0; r < K4_ROWS; ++r) {
        const float mu = fin[r][0], inv = fin[r][1];
        out[(size_t)(row0 + r) * D_MODEL + tid] = fmaf((y[r] - mu) * inv, gv, bv);
    }
}

extern "C" void kernel_launch(void* const* d_in, const int* in_sizes, int n_in,
                              void* d_out, int out_size, void* d_ws, size_t ws_size,
                              hipStream_t stream) {
    (void)in_sizes; (void)n_in; (void)out_size; (void)ws_size;
    const float* x     = (const float*)d_in[0];
    const float* A_log = (const float*)d_in[1];
    const float* B_w   = (const float*)d_in[2];
    const float* C_w   = (const float*)d_in[3];
    const float* Dp    = (const float*)d_in[4];
    const float* gamma = (const float*)d_in[5];
    const float* beta  = (const float*)d_in[6];
    float* out = (float*)d_out;

    float* bx = (float*)d_ws;                       // ROWS*16 floats (512 KB)
    float* kb = bx + (size_t)ROWS * D_STATE;        // WIN*16 floats (4 KB)

    k_bx  <<<ROWS / K1_ROWS, 256,  0, stream>>>(x, B_w, bx);
    k_kbar<<<D_STATE,        256,  0, stream>>>(A_log, kb);
    k_out <<<ROWS / K4_ROWS, 1024, 0, stream>>>(x, bx, kb, C_w, Dp, gamma, beta, out);
}

// Round 5
// 57.762 us; speedup vs baseline: 1.4639x; 1.3110x over previous
//
#include <hip/hip_runtime.h>
#include <hip/hip_bf16.h>

#define D_MODEL 1024
#define D_STATE 16
#define BATCH   4
#define SEQ     2048
#define ROWS    (BATCH*SEQ)   // 8192
#define WIN     64            // FIR window; decay<=0.55 => decay^64 < 1e-16

// ---------------------------------------------------------------------------
// K1: bx[row][n] = sum_d x[row][d] * B_w[n][d]
// 256 threads = 32 dblk x 8 n-pairs, 8 rows/block, swizzled LDS staging.
// (unchanged from R4)
// ---------------------------------------------------------------------------
#define K1_ROWS 8
__global__ __launch_bounds__(256, 4) void k_bx(const float* __restrict__ x,
                                               const float* __restrict__ Bw,
                                               float* __restrict__ bx) {
    __shared__ float xs[K1_ROWS][1024];
    __shared__ float red[4][8][K1_ROWS][2];   // [wave][np][row][q]
    const int tid  = threadIdx.x;
    const int np   = tid & 7;
    const int dblk = tid >> 3;
    const int row0 = blockIdx.x * K1_ROWS;
    const int lane = tid & 63, wid = tid >> 6;

    float4 bw0[8], bw1[8];
    {
        const float4* p0 = reinterpret_cast<const float4*>(Bw + (size_t)(2 * np    ) * 1024 + dblk * 32);
        const float4* p1 = reinterpret_cast<const float4*>(Bw + (size_t)(2 * np + 1) * 1024 + dblk * 32);
#pragma unroll
        for (int j = 0; j < 8; ++j) { bw0[j] = p0[j]; bw1[j] = p1[j]; }
    }

    const int chunk = tid >> 3;
    const int slotw = ((tid & 7) + chunk) & 7;
#pragma unroll
    for (int r = 0; r < K1_ROWS; ++r) {
        float4 v = reinterpret_cast<const float4*>(x + (size_t)(row0 + r) * 1024)[tid];
        *reinterpret_cast<float4*>(&xs[r][chunk * 32 + slotw * 4]) = v;
    }
    __syncthreads();

    float a0[K1_ROWS], a1[K1_ROWS];
#pragma unroll
    for (int r = 0; r < K1_ROWS; ++r) { a0[r] = 0.f; a1[r] = 0.f; }

#pragma unroll
    for (int r = 0; r < K1_ROWS; ++r) {
#pragma unroll
        for (int j = 0; j < 8; ++j) {
            const int slot = (j + dblk) & 7;
            float4 xv = *reinterpret_cast<const float4*>(&xs[r][dblk * 32 + slot * 4]);
            a0[r] = fmaf(xv.x, bw0[j].x, a0[r]); a0[r] = fmaf(xv.y, bw0[j].y, a0[r]);
            a0[r] = fmaf(xv.z, bw0[j].z, a0[r]); a0[r] = fmaf(xv.w, bw0[j].w, a0[r]);
            a1[r] = fmaf(xv.x, bw1[j].x, a1[r]); a1[r] = fmaf(xv.y, bw1[j].y, a1[r]);
            a1[r] = fmaf(xv.z, bw1[j].z, a1[r]); a1[r] = fmaf(xv.w, bw1[j].w, a1[r]);
        }
    }

#pragma unroll
    for (int r = 0; r < K1_ROWS; ++r) {
        float v0 = a0[r], v1 = a1[r];
        v0 += __shfl_xor(v0, 8);  v1 += __shfl_xor(v1, 8);
        v0 += __shfl_xor(v0, 16); v1 += __shfl_xor(v1, 16);
        v0 += __shfl_xor(v0, 32); v1 += __shfl_xor(v1, 32);
        a0[r] = v0; a1[r] = v1;
    }
    if (lane < 8) {
#pragma unroll
        for (int r = 0; r < K1_ROWS; ++r) {
            red[wid][lane][r][0] = a0[r];
            red[wid][lane][r][1] = a1[r];
        }
    }
    __syncthreads();
    if (tid < K1_ROWS * 16) {
        const int r = tid >> 4, n = tid & 15;
        float v = red[0][n >> 1][r][n & 1] + red[1][n >> 1][r][n & 1]
                + red[2][n >> 1][r][n & 1] + red[3][n >> 1][r][n & 1];
        bx[(size_t)(row0 + r) * D_STATE + n] = v;
    }
}

// ---------------------------------------------------------------------------
// K2: KbarT[delta][n] = (1/1024) * sum_d decay[d][n]^delta   (delta-parallel)
// ---------------------------------------------------------------------------
__global__ __launch_bounds__(256) void k_kbar(const float* __restrict__ A_log,
                                              float* __restrict__ KbarT) {
    const int n = blockIdx.x;
    const int tid = threadIdx.x;
    const int delta = tid & 63;
    const int c     = tid >> 6;
    __shared__ float l2[D_MODEL];
    __shared__ float red[4][WIN];

    for (int d = tid; d < D_MODEL; d += 256) {
        float a = A_log[d * D_STATE + n];
        l2[d] = -expf(a) * 1.4426950408889634f;
    }
    __syncthreads();

    const float fdelta = (float)delta;
    float acc = 0.f;
    const int d0 = c * 256;
    for (int d = d0; d < d0 + 256; ++d)
        acc += exp2f(fdelta * l2[d]);
    red[c][delta] = acc;
    __syncthreads();
    if (tid < WIN)
        KbarT[tid * D_STATE + n] =
            (red[0][tid] + red[1][tid] + red[2][tid] + red[3][tid]) * (1.0f / 1024.0f);
}

// ---------------------------------------------------------------------------
// K3: FIR, float4 over n. 256 thr = 64 rows x 4 n-quads, grid 128.
// hm[row][nq] = sum_delta kb[delta][nq] * bx[row-delta][nq]  (float4)
// ---------------------------------------------------------------------------
__global__ __launch_bounds__(256) void k_fir(const float* __restrict__ bx,
                                             const float* __restrict__ KbarT,
                                             float* __restrict__ hm) {
    __shared__ float4 kb4[WIN][4];
    const int tid = threadIdx.x;
    kb4[tid >> 2][tid & 3] = reinterpret_cast<const float4*>(KbarT)[tid];
    __syncthreads();

    const int nq  = tid & 3;
    const int row = blockIdx.x * 64 + (tid >> 2);
    const int t   = row & (SEQ - 1);
    const float4* bp = reinterpret_cast<const float4*>(bx + (size_t)row * D_STATE) + nq;
    float4 acc = {0.f, 0.f, 0.f, 0.f};
    if (t >= WIN - 1) {
#pragma unroll
        for (int dl = 0; dl < WIN; ++dl) {
            float4 b = bp[-(ptrdiff_t)dl * 4];
            float4 k = kb4[dl][nq];
            acc.x = fmaf(k.x, b.x, acc.x); acc.y = fmaf(k.y, b.y, acc.y);
            acc.z = fmaf(k.z, b.z, acc.z); acc.w = fmaf(k.w, b.w, acc.w);
        }
    } else {
        for (int dl = 0; dl <= t; ++dl) {
            float4 b = bp[-(ptrdiff_t)dl * 4];
            float4 k = kb4[dl][nq];
            acc.x = fmaf(k.x, b.x, acc.x); acc.y = fmaf(k.y, b.y, acc.y);
            acc.z = fmaf(k.z, b.z, acc.z); acc.w = fmaf(k.w, b.w, acc.w);
        }
    }
    reinterpret_cast<float4*>(hm + (size_t)row * D_STATE)[nq] = acc;
}

// ---------------------------------------------------------------------------
// K4: y = hm @ C_w^T + D*x ; out = LN(y)*gamma + beta. Fully float4.
// 256 thr, thread owns d-quad tid; 4 rows/block, grid 2048; 1 barrier.
// hm read as uniform (scalar-path) global loads; C_w quad-slice in 64 VGPRs.
// ---------------------------------------------------------------------------
#define KO_ROWS 4
__global__ __launch_bounds__(256, 4) void k_out(const float* __restrict__ x,
                                                const float* __restrict__ hm,
                                                const float* __restrict__ Cw,
                                                const float* __restrict__ Dp,
                                                const float* __restrict__ gamma,
                                                const float* __restrict__ beta,
                                                float* __restrict__ out) {
    const int tid = threadIdx.x;
    const int row0 = blockIdx.x * KO_ROWS;
    const int lane = tid & 63, wid = tid >> 6;
    __shared__ float red_s[KO_ROWS][4], red_q[KO_ROWS][4];

    // cw[j][q] = C_w[4*tid+j][4q .. 4q+3]
    float4 cw[4][4];
#pragma unroll
    for (int j = 0; j < 4; ++j) {
        const float4* p = reinterpret_cast<const float4*>(Cw + (size_t)(tid * 4 + j) * D_STATE);
#pragma unroll
        for (int q = 0; q < 4; ++q) cw[j][q] = p[q];
    }
    const float4 Dq = reinterpret_cast<const float4*>(Dp)[tid];
    const float4 gq = reinterpret_cast<const float4*>(gamma)[tid];
    const float4 bq = reinterpret_cast<const float4*>(beta)[tid];

    float4 y[KO_ROWS];
#pragma unroll
    for (int r = 0; r < KO_ROWS; ++r) {
        const size_t row = row0 + r;
        const float4* hp = reinterpret_cast<const float4*>(hm + row * D_STATE);
        const float4 h0 = hp[0], h1 = hp[1], h2 = hp[2], h3 = hp[3];  // uniform
        const float4 xq = reinterpret_cast<const float4*>(x + row * D_MODEL)[tid];

        float4 v;
#pragma unroll
        for (int j = 0; j < 4; ++j) {
            float a = 0.f;
            a = fmaf(h0.x, cw[j][0].x, a); a = fmaf(h0.y, cw[j][0].y, a);
            a = fmaf(h0.z, cw[j][0].z, a); a = fmaf(h0.w, cw[j][0].w, a);
            a = fmaf(h1.x, cw[j][1].x, a); a = fmaf(h1.y, cw[j][1].y, a);
            a = fmaf(h1.z, cw[j][1].z, a); a = fmaf(h1.w, cw[j][1].w, a);
            a = fmaf(h2.x, cw[j][2].x, a); a = fmaf(h2.y, cw[j][2].y, a);
            a = fmaf(h2.z, cw[j][2].z, a); a = fmaf(h2.w, cw[j][2].w, a);
            a = fmaf(h3.x, cw[j][3].x, a); a = fmaf(h3.y, cw[j][3].y, a);
            a = fmaf(h3.z, cw[j][3].z, a); a = fmaf(h3.w, cw[j][3].w, a);
            ((float*)&v)[j] = a;
        }
        v.x = fmaf(Dq.x, xq.x, v.x);
        v.y = fmaf(Dq.y, xq.y, v.y);
        v.z = fmaf(Dq.z, xq.z, v.z);
        v.w = fmaf(Dq.w, xq.w, v.w);
        y[r] = v;

        float s  = v.x + v.y + v.z + v.w;
        float sq = v.x*v.x + v.y*v.y + v.z*v.z + v.w*v.w;
        s += __shfl_xor(s, 1);  sq += __shfl_xor(sq, 1);
        s += __shfl_xor(s, 2);  sq += __shfl_xor(sq, 2);
        s += __shfl_xor(s, 4);  sq += __shfl_xor(sq, 4);
        s += __shfl_xor(s, 8);  sq += __shfl_xor(sq, 8);
        s += __shfl_xor(s, 16); sq += __shfl_xor(sq, 16);
        s += __shfl_xor(s, 32); sq += __shfl_xor(sq, 32);
        if (lane == 0) { red_s[r][wid] = s; red_q[r][wid] = sq; }
    }
    __syncthreads();

#pragma unroll
    for (int r = 0; r < KO_ROWS; ++r) {
        const size_t row = row0 + r;
        const float ssum = red_s[r][0] + red_s[r][1] + red_s[r][2] + red_s[r][3];
        const float ssq  = red_q[r][0] + red_q[r][1] + red_q[r][2] + red_q[r][3];
        const float mu   = ssum * (1.0f / 1024.0f);
        const float var  = ssq * (1.0f / 1024.0f) - mu * mu;
        const float inv  = rsqrtf(var + 1e-5f);
        const float4 v = y[r];
        float4 o;
        o.x = fmaf((v.x - mu) * inv, gq.x, bq.x);
        o.y = fmaf((v.y - mu) * inv, gq.y, bq.y);
        o.z = fmaf((v.z - mu) * inv, gq.z, bq.z);
        o.w = fmaf((v.w - mu) * inv, gq.w, bq.w);
        reinterpret_cast<float4*>(out + row * D_MODEL)[tid] = o;
    }
}

extern "C" void kernel_launch(void* const* d_in, const int* in_sizes, int n_in,
                              void* d_out, int out_size, void* d_ws, size_t ws_size,
                              hipStream_t stream) {
    (void)in_sizes; (void)n_in; (void)out_size; (void)ws_size;
    const float* x     = (const float*)d_in[0];
    const float* A_log = (const float*)d_in[1];
    const float* B_w   = (const float*)d_in[2];
    const float* C_w   = (const float*)d_in[3];
    const float* Dp    = (const float*)d_in[4];
    const float* gamma = (const float*)d_in[5];
    const float* beta  = (const float*)d_in[6];
    float* out = (float*)d_out;

    float* bx = (float*)d_ws;                       // ROWS*16 floats (512 KB)
    float* kb = bx + (size_t)ROWS * D_STATE;        // WIN*16 floats (4 KB)
    float* hm = kb + WIN * D_STATE;                 // ROWS*16 floats (512 KB)

    k_bx  <<<ROWS / K1_ROWS, 256, 0, stream>>>(x, B_w, bx);
    k_kbar<<<D_STATE,        256, 0, stream>>>(A_log, kb);
    k_fir <<<ROWS / 64,      256, 0, stream>>>(bx, kb, hm);
    k_out <<<ROWS / KO_ROWS, 256, 0, stream>>>(x, hm, C_w, Dp, gamma, beta, out);
}